// Round 1
// baseline (717.705 us; speedup 1.0000x reference)
//
#include <hip/hip_runtime.h>
#include <stdint.h>

#define NN 10000     // nodes
#define NE 320000    // edges
#define KK 256       // IN
#define DO 128       // OUT

typedef __attribute__((ext_vector_type(8))) short bf16x8;
typedef __attribute__((ext_vector_type(4))) short bf16x4;
typedef __attribute__((ext_vector_type(4))) float f32x4;
typedef __attribute__((ext_vector_type(2))) float f32x2;

static __device__ __forceinline__ unsigned short f2bf(float x) {
  union { float f; uint32_t u; } v; v.f = x;
  return (unsigned short)((v.u + 0x7FFFu + ((v.u >> 16) & 1u)) >> 16);  // RNE
}
static __device__ __forceinline__ float bf2f(uint32_t bits16) {
  union { uint32_t u; float f; } v; v.u = bits16 << 16;
  return v.f;
}

// ---------------------------------------------------------------------------
// prep: build bf16 weight images in the exact LDS layout the GEMM reads.
// Image group (chunk c, col, slot s): 8 bf16 = Wt[col][k0..k0+8),
//   k0 = c*32 + ((s ^ ((col>>1)&3)) << 3)   (slot-XOR swizzle for LDS banks)
// Edge image: 256 cols = [W_prj_edge | W_edge]. Node images: 5 mats x 128 cols.
// Also bsum[c] = b_prj_src + b_prj_dst + b_prj_edge.
// ---------------------------------------------------------------------------
__global__ void prep_kernel(const float* __restrict__ Wpe, const float* __restrict__ We,
                            const float* __restrict__ W0, const float* __restrict__ W1,
                            const float* __restrict__ W2, const float* __restrict__ W3,
                            const float* __restrict__ W4,
                            const float* __restrict__ bps, const float* __restrict__ bpd,
                            const float* __restrict__ bpe,
                            short* __restrict__ img_edge, short* __restrict__ img_node,
                            float* __restrict__ bsum) {
  int gid = blockIdx.x * 256 + threadIdx.x;
  if (gid < DO) bsum[gid] = bps[gid] + bpd[gid] + bpe[gid];
  const int EG = 8 * 256 * 4;   // 8192 edge groups
  const int NG = 8 * 128 * 4;   // 4096 groups per node mat
  if (gid >= EG + 5 * NG) return;
  const float* W; int col, c, s; short* dstp;
  if (gid < EG) {
    c = gid >> 10; int rem = gid & 1023; col = rem >> 2; s = rem & 3;
    W = (col < DO) ? (Wpe + col) : (We + (col - DO));
    dstp = img_edge + (size_t)gid * 8;
  } else {
    int g = gid - EG; int m = g >> 12; int rem = g & 4095;
    c = rem >> 9; int r2 = rem & 511; col = r2 >> 2; s = r2 & 3;
    const float* Wm = (m == 0) ? W0 : (m == 1) ? W1 : (m == 2) ? W2 : (m == 3) ? W3 : W4;
    W = Wm + col;
    dstp = img_node + (size_t)g * 8;
  }
  int k0 = c * 32 + ((s ^ ((col >> 1) & 3)) << 3);
  short tmp[8];
#pragma unroll
  for (int i = 0; i < 8; ++i) tmp[i] = (short)f2bf(W[(size_t)(k0 + i) * DO]);
  *(bf16x8*)dstp = *(const bf16x8*)tmp;
}

// ---------------------------------------------------------------------------
// Swapped-operand MFMA GEMM:  out[row][col] = sum_k A[row][k] * W[k][col]
// computed as D = Wt_frag (A-operand) x Act^T_frag (B-operand) so that each
// lane owns 4 CONSECUTIVE output cols of one row -> direct 8B/16B stores.
// Block: 256 thr / 4 waves; wave = 32 rows x NC cols; K-chunks of 32, dbuf LDS.
// grid.y selects node matrix (0-2 bf16 out, 3-4 f32 out); edge uses NCF=16,y=0.
// ---------------------------------------------------------------------------
template <int NCF>
__global__ __launch_bounds__(256, 2) void gemm_kernel(
    const float* __restrict__ A, int M,
    const short* __restrict__ img_all,
    short* __restrict__ ob0, short* __restrict__ ob1, short* __restrict__ ob2,
    float* __restrict__ of3, float* __restrict__ of4) {
  constexpr int NC = NCF * 16;
  constexpr int CHUNK = NC * 64;        // bytes per k-chunk image
  constexpr int ROUNDS = CHUNK / 4096;  // 16B/thread/round
  __shared__ char lds[2 * CHUNK];

  const int tid = threadIdx.x;
  const int wv = tid >> 6;
  const int ln = tid & 63;
  const int l15 = ln & 15;
  const int l4 = ln >> 4;
  const int by = blockIdx.y;
  const short* __restrict__ img = img_all + (size_t)by * (8 * CHUNK / 2);
  const int row_base = blockIdx.x * 128 + wv * 32;
  const int rd_off = l15 * 64 + ((l4 ^ ((l15 >> 1) & 3)) << 4);  // swizzled frag addr

  f32x4 acc[2][NCF];
#pragma unroll
  for (int e = 0; e < 2; ++e)
#pragma unroll
    for (int f = 0; f < NCF; ++f) acc[e][f] = (f32x4)0.f;

  // stage chunk 0
#pragma unroll
  for (int r = 0; r < ROUNDS; ++r) {
    int off = r * 4096 + tid * 16;
    *(bf16x8*)(lds + off) = *(const bf16x8*)((const char*)img + off);
  }
  __syncthreads();

  for (int c = 0; c < 8; ++c) {
    const int cur = c & 1;
    // prefetch next weight chunk to regs (hidden under MFMA)
    bf16x8 nx[ROUNDS];
    if (c < 7) {
#pragma unroll
      for (int r = 0; r < ROUNDS; ++r) {
        int off = r * 4096 + tid * 16;
        nx[r] = *(const bf16x8*)((const char*)img + (size_t)(c + 1) * CHUNK + off);
      }
    }
    // A (activation) loads straight from global f32, convert to bf16 frags
    bf16x8 af[2];
#pragma unroll
    for (int e = 0; e < 2; ++e) {
      int row = row_base + e * 16 + l15;
      f32x4 lo = (f32x4)0.f, hi = (f32x4)0.f;
      if (row < M) {
        const float* ap = A + (size_t)row * KK + c * 32 + l4 * 8;
        lo = *(const f32x4*)ap;
        hi = *(const f32x4*)(ap + 4);
      }
      bf16x8 t;
#pragma unroll
      for (int j = 0; j < 4; ++j) { t[j] = (short)f2bf(lo[j]); t[4 + j] = (short)f2bf(hi[j]); }
      af[e] = t;
    }
    // MFMA: each W-frag reused for both row frags
    const char* buf = lds + cur * CHUNK;
#pragma unroll
    for (int f = 0; f < NCF; ++f) {
      bf16x8 wf = *(const bf16x8*)(buf + f * 1024 + rd_off);
      acc[0][f] = __builtin_amdgcn_mfma_f32_16x16x32_bf16(wf, af[0], acc[0][f], 0, 0, 0);
      acc[1][f] = __builtin_amdgcn_mfma_f32_16x16x32_bf16(wf, af[1], acc[1][f], 0, 0, 0);
    }
    // write next chunk into the other buffer
    if (c < 7) {
#pragma unroll
      for (int r = 0; r < ROUNDS; ++r) {
        int off = r * 4096 + tid * 16;
        *(bf16x8*)(lds + (cur ^ 1) * CHUNK + off) = nx[r];
      }
    }
    __syncthreads();
  }

  // epilogue: lane owns cols [f*16 + l4*4 .. +4) of row (row_base + e*16 + l15)
  short* ob = (by == 0) ? ob0 : (by == 1) ? ob1 : ob2;
  float* of = (by == 3) ? of3 : of4;
  const bool isf = (by >= 3);
#pragma unroll
  for (int e = 0; e < 2; ++e) {
    int row = row_base + e * 16 + l15;
    if (row >= M) continue;
#pragma unroll
    for (int f = 0; f < NCF; ++f) {
      int c0 = f * 16 + l4 * 4;
      f32x4 v = acc[e][f];
      if (!isf) {
        bf16x4 p;
#pragma unroll
        for (int j = 0; j < 4; ++j) p[j] = (short)f2bf(v[j]);
        *(bf16x4*)(ob + (size_t)row * NC + c0) = p;
      } else {
        *(f32x4*)(of + (size_t)row * NC + c0) = v;
      }
    }
  }
}

// ---------------------------------------------------------------------------
// logit: one wave per edge. w = ew + hw_src[src] + hw_dst[dst] + bsum; PReLU;
// logit = dot(w, W_att) + b_att  (64-lane shfl reduce, 2 cols/lane)
// ---------------------------------------------------------------------------
__global__ void logit_kernel(const short* __restrict__ ewe,
                             const short* __restrict__ hwS, const short* __restrict__ hwD,
                             const float* __restrict__ bsum, const float* __restrict__ Watt,
                             const float* __restrict__ batt, const float* __restrict__ alpha_p,
                             const int* __restrict__ src, const int* __restrict__ dst,
                             float* __restrict__ logits) {
  const int ln = threadIdx.x & 63;
  const int wid = (blockIdx.x * blockDim.x + threadIdx.x) >> 6;
  const int nw = (gridDim.x * blockDim.x) >> 6;
  const float alpha = alpha_p[0], ba = batt[0];
  const int c2 = ln * 2;
  const float bs0 = bsum[c2], bs1 = bsum[c2 + 1];
  const float wa0 = Watt[c2], wa1 = Watt[c2 + 1];
  for (int e = wid; e < NE; e += nw) {
    int s = src[e], d = dst[e];
    uint32_t ew = *(const uint32_t*)(ewe + (size_t)e * 256 + c2);
    uint32_t hs = *(const uint32_t*)(hwS + (size_t)s * 128 + c2);
    uint32_t hd = *(const uint32_t*)(hwD + (size_t)d * 128 + c2);
    float w0 = bf2f(ew & 0xffffu) + bf2f(hs & 0xffffu) + bf2f(hd & 0xffffu) + bs0;
    float w1 = bf2f(ew >> 16) + bf2f(hs >> 16) + bf2f(hd >> 16) + bs1;
    w0 = (w0 >= 0.f) ? w0 : alpha * w0;
    w1 = (w1 >= 0.f) ? w1 : alpha * w1;
    float p = w0 * wa0 + w1 * wa1;
#pragma unroll
    for (int o = 32; o > 0; o >>= 1) p += __shfl_xor(p, o, 64);
    if (ln == 0) logits[e] = p + ba;
  }
}

// --------------------------- CSR build (no float atomics later) -------------
__global__ void count_kernel(const int* __restrict__ dst, int* __restrict__ deg) {
  int e = blockIdx.x * 256 + threadIdx.x;
  if (e < NE) atomicAdd(&deg[dst[e]], 1);
}

__global__ void scan_kernel(const int* __restrict__ deg, int* __restrict__ offs,
                            int* __restrict__ cursor) {
  __shared__ int sm[1024];
  const int tid = threadIdx.x;
  int loc[10];
  int s = 0;
#pragma unroll
  for (int i = 0; i < 10; ++i) {
    int idx = tid * 10 + i;
    int d = (idx < NN) ? deg[idx] : 0;
    loc[i] = s; s += d;
  }
  sm[tid] = s;
  __syncthreads();
  for (int d = 1; d < 1024; d <<= 1) {
    int t = (tid >= d) ? sm[tid - d] : 0;
    __syncthreads();
    sm[tid] += t;
    __syncthreads();
  }
  int base = (tid == 0) ? 0 : sm[tid - 1];
#pragma unroll
  for (int i = 0; i < 10; ++i) {
    int idx = tid * 10 + i;
    if (idx < NN) { int v = base + loc[i]; offs[idx] = v; cursor[idx] = v; }
  }
  if (tid == 1023) offs[NN] = base + s;   // = NE
}

__global__ void scatter_kernel(const int* __restrict__ dst, int* __restrict__ cursor,
                               int* __restrict__ eids) {
  int e = blockIdx.x * 256 + threadIdx.x;
  if (e < NE) {
    int p = atomicAdd(&cursor[dst[e]], 1);
    eids[p] = e;
  }
}

// ---------------------------------------------------------------------------
// reduce: one wave per dst node. Pass1 max logit; pass2 accumulate
// den = sum p,  acc = sum p*(e+b_edge)*h_src[src];  out = h_self + bias +
// h_dst * acc/den  (h_dst factored out of the per-edge product).
// ---------------------------------------------------------------------------
__global__ void reduce_kernel(const int* __restrict__ offs, const int* __restrict__ eids,
                              const int* __restrict__ src, const float* __restrict__ logits,
                              const short* __restrict__ ewe, const short* __restrict__ hsB,
                              const float* __restrict__ hdst, const float* __restrict__ hself,
                              const float* __restrict__ b_edge, const float* __restrict__ bias,
                              float* __restrict__ out) {
  const int node = (blockIdx.x * blockDim.x + threadIdx.x) >> 6;
  const int ln = threadIdx.x & 63;
  if (node >= NN) return;
  const int b0 = offs[node], b1 = offs[node + 1];
  const int deg = b1 - b0;
  const int c2 = ln * 2;
  const float be0 = b_edge[c2], be1 = b_edge[c2 + 1];

  float mx = -1e30f;
  for (int i = ln; i < deg; i += 64) mx = fmaxf(mx, logits[eids[b0 + i]]);
#pragma unroll
  for (int o = 32; o > 0; o >>= 1) mx = fmaxf(mx, __shfl_xor(mx, o, 64));

  float den = 0.f, a0 = 0.f, a1 = 0.f;
  for (int i = 0; i < deg; ++i) {
    int e = eids[b0 + i];
    float p = __expf(logits[e] - mx);
    uint32_t ee = *(const uint32_t*)(ewe + (size_t)e * 256 + 128 + c2);
    int sn = src[e];
    uint32_t hh = *(const uint32_t*)(hsB + (size_t)sn * 128 + c2);
    a0 += p * (bf2f(ee & 0xffffu) + be0) * bf2f(hh & 0xffffu);
    a1 += p * (bf2f(ee >> 16) + be1) * bf2f(hh >> 16);
    den += p;
  }
  float inv = (deg > 0) ? 1.0f / den : 0.f;
  f32x2 hd = *(const f32x2*)(hdst + (size_t)node * 128 + c2);
  f32x2 hs = *(const f32x2*)(hself + (size_t)node * 128 + c2);
  f32x2 bb = *(const f32x2*)(bias + c2);
  f32x2 o;
  o[0] = hs[0] + bb[0] + hd[0] * a0 * inv;
  o[1] = hs[1] + bb[1] + hd[1] * a1 * inv;
  *(f32x2*)(out + (size_t)node * 128 + c2) = o;
}

// ---------------------------------------------------------------------------
extern "C" void kernel_launch(void* const* d_in, const int* in_sizes, int n_in,
                              void* d_out, int out_size, void* d_ws, size_t ws_size,
                              hipStream_t stream) {
  const float* feat      = (const float*)d_in[0];
  const float* edge_w    = (const float*)d_in[1];
  const float* W_neigh   = (const float*)d_in[2];
  const float* W_dstM    = (const float*)d_in[3];
  const float* W_self    = (const float*)d_in[4];
  const float* W_edge    = (const float*)d_in[5];
  const float* b_edge    = (const float*)d_in[6];
  const float* W_prj_src = (const float*)d_in[7];
  const float* b_prj_src = (const float*)d_in[8];
  const float* W_prj_dst = (const float*)d_in[9];
  const float* b_prj_dst = (const float*)d_in[10];
  const float* W_prj_edge= (const float*)d_in[11];
  const float* b_prj_edge= (const float*)d_in[12];
  const float* alpha     = (const float*)d_in[13];
  const float* W_att     = (const float*)d_in[14];
  const float* b_att     = (const float*)d_in[15];
  const float* bias      = (const float*)d_in[16];
  const int*   src       = (const int*)d_in[17];
  const int*   dst       = (const int*)d_in[18];
  float* out = (float*)d_out;

  char* ws = (char*)d_ws;
  size_t off = 0;
  auto alloc = [&](size_t bytes) -> void* {
    void* p = ws + off;
    off = (off + bytes + 511) & ~(size_t)511;
    return p;
  };
  short* img_edge = (short*)alloc((size_t)8 * 256 * 64);       // 128 KB
  short* img_node = (short*)alloc((size_t)5 * 8 * 128 * 64);   // 320 KB
  float* bsum     = (float*)alloc(128 * 4);
  short* hwS      = (short*)alloc((size_t)NN * 128 * 2);
  short* hwD      = (short*)alloc((size_t)NN * 128 * 2);
  short* hsB      = (short*)alloc((size_t)NN * 128 * 2);
  float* hdst     = (float*)alloc((size_t)NN * 128 * 4);
  float* hself    = (float*)alloc((size_t)NN * 128 * 4);
  float* logits   = (float*)alloc((size_t)NE * 4);
  short* ewe      = (short*)alloc((size_t)NE * 256 * 2);       // 164 MB
  int*   deg      = (int*)alloc((size_t)NN * 4);
  int*   offsb    = (int*)alloc((size_t)(NN + 1) * 4);
  int*   cursor   = (int*)alloc((size_t)NN * 4);
  int*   eids     = (int*)alloc((size_t)NE * 4);
  // total ~186 MB of ws

  hipMemsetAsync(deg, 0, (size_t)NN * 4, stream);

  prep_kernel<<<dim3(112), 256, 0, stream>>>(
      W_prj_edge, W_edge, W_prj_src, W_prj_dst, W_neigh, W_dstM, W_self,
      b_prj_src, b_prj_dst, b_prj_edge, img_edge, img_node, bsum);

  // 5 node GEMMs: hwS,hwD,hsB (bf16) / hdst,hself (f32)
  gemm_kernel<8><<<dim3(79, 5), 256, 0, stream>>>(feat, NN, img_node,
                                                  hwS, hwD, hsB, hdst, hself);
  // edge GEMM: ewe[E][256] = [edge_w@W_prj_edge | edge_w@W_edge] (bf16, no bias)
  gemm_kernel<16><<<dim3(NE / 128, 1), 256, 0, stream>>>(edge_w, NE, img_edge,
                                                         ewe, nullptr, nullptr,
                                                         nullptr, nullptr);

  logit_kernel<<<dim3(2048), 256, 0, stream>>>(ewe, hwS, hwD, bsum, W_att, b_att,
                                               alpha, src, dst, logits);

  count_kernel<<<dim3((NE + 255) / 256), 256, 0, stream>>>(dst, deg);
  scan_kernel<<<dim3(1), 1024, 0, stream>>>(deg, offsb, cursor);
  scatter_kernel<<<dim3((NE + 255) / 256), 256, 0, stream>>>(dst, cursor, eids);

  reduce_kernel<<<dim3(NN / 4), 256, 0, stream>>>(offsb, eids, src, logits, ewe,
                                                  hsB, hdst, hself, b_edge, bias, out);
}

// Round 2
// 693.686 us; speedup vs baseline: 1.0346x; 1.0346x over previous
//
#include <hip/hip_runtime.h>
#include <stdint.h>

#define NN 10000     // nodes
#define NE 320000    // edges
#define KK 256       // IN
#define DO 128       // OUT

typedef __attribute__((ext_vector_type(8))) short bf16x8;
typedef __attribute__((ext_vector_type(4))) short bf16x4;
typedef __attribute__((ext_vector_type(4))) float f32x4;
typedef __attribute__((ext_vector_type(2))) float f32x2;

static __device__ __forceinline__ unsigned short f2bf(float x) {
  union { float f; uint32_t u; } v; v.f = x;
  return (unsigned short)((v.u + 0x7FFFu + ((v.u >> 16) & 1u)) >> 16);  // RNE
}
static __device__ __forceinline__ float bf2f(uint32_t bits16) {
  union { uint32_t u; float f; } v; v.u = bits16 << 16;
  return v.f;
}

// ---------------------------------------------------------------------------
// prep: build bf16 weight images in the exact LDS layout the GEMM reads.
// Group (chunk c, col, slot s): 8 bf16 = Wt[col][k0..k0+8),
//   k0 = c*32 + ((s ^ ((col>>1)&3)) << 3)   (slot-XOR swizzle for LDS banks)
// Edge image: 256 cols = [W_prj_edge | W_edge]. Node images: 5 mats x 128 cols.
// ---------------------------------------------------------------------------
__global__ void nig_prep(const float* __restrict__ Wpe, const float* __restrict__ We,
                         const float* __restrict__ W0, const float* __restrict__ W1,
                         const float* __restrict__ W2, const float* __restrict__ W3,
                         const float* __restrict__ W4,
                         const float* __restrict__ bps, const float* __restrict__ bpd,
                         const float* __restrict__ bpe,
                         short* __restrict__ img_edge, short* __restrict__ img_node,
                         float* __restrict__ bsum) {
  int gid = blockIdx.x * 256 + threadIdx.x;
  if (gid < DO) bsum[gid] = bps[gid] + bpd[gid] + bpe[gid];
  const int EG = 8 * 256 * 4;   // 8192 edge groups
  const int NG = 8 * 128 * 4;   // 4096 groups per node mat
  if (gid >= EG + 5 * NG) return;
  const float* W; int col, c, s; short* dstp;
  if (gid < EG) {
    c = gid >> 10; int rem = gid & 1023; col = rem >> 2; s = rem & 3;
    W = (col < DO) ? (Wpe + col) : (We + (col - DO));
    dstp = img_edge + (size_t)gid * 8;
  } else {
    int g = gid - EG; int m = g >> 12; int rem = g & 4095;
    c = rem >> 9; int r2 = rem & 511; col = r2 >> 2; s = r2 & 3;
    const float* Wm = (m == 0) ? W0 : (m == 1) ? W1 : (m == 2) ? W2 : (m == 3) ? W3 : W4;
    W = Wm + col;
    dstp = img_node + (size_t)g * 8;
  }
  int k0 = c * 32 + ((s ^ ((col >> 1) & 3)) << 3);
  short tmp[8];
#pragma unroll
  for (int i = 0; i < 8; ++i) tmp[i] = (short)f2bf(W[(size_t)(k0 + i) * DO]);
  *(bf16x8*)dstp = *(const bf16x8*)tmp;
}

// ---------------------------------------------------------------------------
// Node GEMM (NC=128): swapped-operand MFMA, lane owns 4 consecutive out cols.
// grid.y: 0-2 bf16 outputs (hwS,hwD,hsB), 3-4 f32 outputs (hdst,hself).
// ---------------------------------------------------------------------------
__global__ __launch_bounds__(256, 2) void nig_gemm_node(
    const float* __restrict__ A, int M,
    const short* __restrict__ img_all,
    short* __restrict__ ob0, short* __restrict__ ob1, short* __restrict__ ob2,
    float* __restrict__ of3, float* __restrict__ of4) {
  constexpr int NCF = 8;
  constexpr int NC = NCF * 16;
  constexpr int CHUNK = NC * 64;
  constexpr int ROUNDS = CHUNK / 4096;
  __shared__ char lds[2 * CHUNK];

  const int tid = threadIdx.x;
  const int wv = tid >> 6;
  const int ln = tid & 63;
  const int l15 = ln & 15;
  const int l4 = ln >> 4;
  const int by = blockIdx.y;
  const short* __restrict__ img = img_all + (size_t)by * (8 * CHUNK / 2);
  const int row_base = blockIdx.x * 128 + wv * 32;
  const int rd_off = l15 * 64 + ((l4 ^ ((l15 >> 1) & 3)) << 4);

  f32x4 acc[2][NCF];
#pragma unroll
  for (int e = 0; e < 2; ++e)
#pragma unroll
    for (int f = 0; f < NCF; ++f) acc[e][f] = (f32x4)0.f;

#pragma unroll
  for (int r = 0; r < ROUNDS; ++r) {
    int off = r * 4096 + tid * 16;
    *(bf16x8*)(lds + off) = *(const bf16x8*)((const char*)img + off);
  }
  __syncthreads();

  for (int c = 0; c < 8; ++c) {
    const int cur = c & 1;
    bf16x8 nx[ROUNDS];
    if (c < 7) {
#pragma unroll
      for (int r = 0; r < ROUNDS; ++r) {
        int off = r * 4096 + tid * 16;
        nx[r] = *(const bf16x8*)((const char*)img + (size_t)(c + 1) * CHUNK + off);
      }
    }
    bf16x8 af[2];
#pragma unroll
    for (int e = 0; e < 2; ++e) {
      int row = row_base + e * 16 + l15;
      f32x4 lo = (f32x4)0.f, hi = (f32x4)0.f;
      if (row < M) {
        const float* ap = A + (size_t)row * KK + c * 32 + l4 * 8;
        lo = *(const f32x4*)ap;
        hi = *(const f32x4*)(ap + 4);
      }
      bf16x8 t;
#pragma unroll
      for (int j = 0; j < 4; ++j) { t[j] = (short)f2bf(lo[j]); t[4 + j] = (short)f2bf(hi[j]); }
      af[e] = t;
    }
    const char* buf = lds + cur * CHUNK;
#pragma unroll
    for (int f = 0; f < NCF; ++f) {
      bf16x8 wf = *(const bf16x8*)(buf + f * 1024 + rd_off);
      acc[0][f] = __builtin_amdgcn_mfma_f32_16x16x32_bf16(wf, af[0], acc[0][f], 0, 0, 0);
      acc[1][f] = __builtin_amdgcn_mfma_f32_16x16x32_bf16(wf, af[1], acc[1][f], 0, 0, 0);
    }
    if (c < 7) {
#pragma unroll
      for (int r = 0; r < ROUNDS; ++r) {
        int off = r * 4096 + tid * 16;
        *(bf16x8*)(lds + (cur ^ 1) * CHUNK + off) = nx[r];
      }
    }
    __syncthreads();
  }

  short* ob = (by == 0) ? ob0 : (by == 1) ? ob1 : ob2;
  float* of = (by == 3) ? of3 : of4;
  const bool isf = (by >= 3);
#pragma unroll
  for (int e = 0; e < 2; ++e) {
    int row = row_base + e * 16 + l15;
    if (row >= M) continue;
#pragma unroll
    for (int f = 0; f < NCF; ++f) {
      int c0 = f * 16 + l4 * 4;
      f32x4 v = acc[e][f];
      if (!isf) {
        bf16x4 p;
#pragma unroll
        for (int j = 0; j < 4; ++j) p[j] = (short)f2bf(v[j]);
        *(bf16x4*)(ob + (size_t)row * NC + c0) = p;
      } else {
        *(f32x4*)(of + (size_t)row * NC + c0) = v;
      }
    }
  }
}

// ---------------------------------------------------------------------------
// Edge GEMM, fused: computes [ew|e] = edge_w @ [W_prj_edge|W_edge]; in the
// epilogue computes the attention logit per row (PReLU + dot W_att + 4-lane
// reduce) and stores logit/src/e-row at the dst-sorted position rank[row].
// e-half is stored with b_edge pre-added. Nothing else materialized.
// ---------------------------------------------------------------------------
__global__ __launch_bounds__(256, 2) void nig_gemm_edge(
    const float* __restrict__ A,
    const short* __restrict__ img,
    const short* __restrict__ hwS, const short* __restrict__ hwD,
    const float* __restrict__ bsum, const float* __restrict__ Watt,
    const float* __restrict__ batt_p, const float* __restrict__ alpha_p,
    const float* __restrict__ b_edge,
    const int* __restrict__ src, const int* __restrict__ dst,
    const int* __restrict__ rank,
    float* __restrict__ logits_s, int* __restrict__ src_s,
    short* __restrict__ ewe_s) {
  constexpr int NCF = 16;
  constexpr int NC = NCF * 16;
  constexpr int CHUNK = NC * 64;        // 16 KB
  constexpr int ROUNDS = CHUNK / 4096;  // 4
  __shared__ char lds[2 * CHUNK];

  const int tid = threadIdx.x;
  const int wv = tid >> 6;
  const int ln = tid & 63;
  const int l15 = ln & 15;
  const int l4 = ln >> 4;
  const int row_base = blockIdx.x * 128 + wv * 32;
  const int rd_off = l15 * 64 + ((l4 ^ ((l15 >> 1) & 3)) << 4);

  f32x4 acc[2][NCF];
#pragma unroll
  for (int e = 0; e < 2; ++e)
#pragma unroll
    for (int f = 0; f < NCF; ++f) acc[e][f] = (f32x4)0.f;

#pragma unroll
  for (int r = 0; r < ROUNDS; ++r) {
    int off = r * 4096 + tid * 16;
    *(bf16x8*)(lds + off) = *(const bf16x8*)((const char*)img + off);
  }
  __syncthreads();

  for (int c = 0; c < 8; ++c) {
    const int cur = c & 1;
    bf16x8 nx[ROUNDS];
    if (c < 7) {
#pragma unroll
      for (int r = 0; r < ROUNDS; ++r) {
        int off = r * 4096 + tid * 16;
        nx[r] = *(const bf16x8*)((const char*)img + (size_t)(c + 1) * CHUNK + off);
      }
    }
    bf16x8 af[2];
#pragma unroll
    for (int e = 0; e < 2; ++e) {
      int row = row_base + e * 16 + l15;
      const float* ap = A + (size_t)row * KK + c * 32 + l4 * 8;
      f32x4 lo = *(const f32x4*)ap;
      f32x4 hi = *(const f32x4*)(ap + 4);
      bf16x8 t;
#pragma unroll
      for (int j = 0; j < 4; ++j) { t[j] = (short)f2bf(lo[j]); t[4 + j] = (short)f2bf(hi[j]); }
      af[e] = t;
    }
    const char* buf = lds + cur * CHUNK;
#pragma unroll
    for (int f = 0; f < NCF; ++f) {
      bf16x8 wf = *(const bf16x8*)(buf + f * 1024 + rd_off);
      acc[0][f] = __builtin_amdgcn_mfma_f32_16x16x32_bf16(wf, af[0], acc[0][f], 0, 0, 0);
      acc[1][f] = __builtin_amdgcn_mfma_f32_16x16x32_bf16(wf, af[1], acc[1][f], 0, 0, 0);
    }
    if (c < 7) {
#pragma unroll
      for (int r = 0; r < ROUNDS; ++r) {
        int off = r * 4096 + tid * 16;
        *(bf16x8*)(lds + (cur ^ 1) * CHUNK + off) = nx[r];
      }
    }
    __syncthreads();
  }

  // --- fused epilogue ---
  const float alpha = alpha_p[0];
  const float batt = batt_p[0];
  const int l4c0 = l4 * 4;
#pragma unroll
  for (int e = 0; e < 2; ++e) {
    const int row = row_base + e * 16 + l15;
    const int s = src[row];
    const int d = dst[row];
    const int rk = rank[row];
    float at = 0.f;
#pragma unroll
    for (int f = 0; f < 8; ++f) {
      const int c0 = f * 16 + l4c0;
      f32x4 v = acc[e][f];
      uint32_t hs0 = *(const uint32_t*)(hwS + (size_t)s * 128 + c0);
      uint32_t hs1 = *(const uint32_t*)(hwS + (size_t)s * 128 + c0 + 2);
      uint32_t hd0 = *(const uint32_t*)(hwD + (size_t)d * 128 + c0);
      uint32_t hd1 = *(const uint32_t*)(hwD + (size_t)d * 128 + c0 + 2);
      f32x4 bs = *(const f32x4*)(bsum + c0);
      f32x4 wa = *(const f32x4*)(Watt + c0);
      float w0 = v[0] + bf2f(hs0 & 0xffffu) + bf2f(hd0 & 0xffffu) + bs[0];
      float w1 = v[1] + bf2f(hs0 >> 16)     + bf2f(hd0 >> 16)     + bs[1];
      float w2 = v[2] + bf2f(hs1 & 0xffffu) + bf2f(hd1 & 0xffffu) + bs[2];
      float w3 = v[3] + bf2f(hs1 >> 16)     + bf2f(hd1 >> 16)     + bs[3];
      w0 = (w0 >= 0.f) ? w0 : alpha * w0;
      w1 = (w1 >= 0.f) ? w1 : alpha * w1;
      w2 = (w2 >= 0.f) ? w2 : alpha * w2;
      w3 = (w3 >= 0.f) ? w3 : alpha * w3;
      at += w0 * wa[0] + w1 * wa[1] + w2 * wa[2] + w3 * wa[3];
    }
    at += __shfl_xor(at, 16, 64);
    at += __shfl_xor(at, 32, 64);
    if (l4 == 0) { logits_s[rk] = at + batt; src_s[rk] = s; }
#pragma unroll
    for (int f = 0; f < 8; ++f) {
      const int c0 = f * 16 + l4c0;
      f32x4 v = acc[e][8 + f];
      f32x4 be = *(const f32x4*)(b_edge + c0);
      bf16x4 p;
#pragma unroll
      for (int j = 0; j < 4; ++j) p[j] = (short)f2bf(v[j] + be[j]);
      *(bf16x4*)(ewe_s + (size_t)rk * 128 + c0) = p;
    }
  }
}

// --------------------------- CSR build --------------------------------------
__global__ void nig_count(const int* __restrict__ dst, int* __restrict__ deg) {
  int e = blockIdx.x * 256 + threadIdx.x;
  if (e < NE) atomicAdd(&deg[dst[e]], 1);
}

__global__ void nig_scan(const int* __restrict__ deg, int* __restrict__ offs,
                         int* __restrict__ cursor) {
  __shared__ int sm[1024];
  const int tid = threadIdx.x;
  int loc[10];
  int s = 0;
#pragma unroll
  for (int i = 0; i < 10; ++i) {
    int idx = tid * 10 + i;
    int d = (idx < NN) ? deg[idx] : 0;
    loc[i] = s; s += d;
  }
  sm[tid] = s;
  __syncthreads();
  for (int d = 1; d < 1024; d <<= 1) {
    int t = (tid >= d) ? sm[tid - d] : 0;
    __syncthreads();
    sm[tid] += t;
    __syncthreads();
  }
  int base = (tid == 0) ? 0 : sm[tid - 1];
#pragma unroll
  for (int i = 0; i < 10; ++i) {
    int idx = tid * 10 + i;
    if (idx < NN) { int v = base + loc[i]; offs[idx] = v; cursor[idx] = v; }
  }
  if (tid == 1023) offs[NN] = base + s;
}

__global__ void nig_scatter(const int* __restrict__ dst, int* __restrict__ cursor,
                            int* __restrict__ rank) {
  int e = blockIdx.x * 256 + threadIdx.x;
  if (e < NE) rank[e] = atomicAdd(&cursor[dst[e]], 1);
}

// ---------------------------------------------------------------------------
// reduce: one wave per dst node; all per-edge data is CSR-sorted -> streaming.
// den = sum p,  acc = sum p * e_s * h_src[src];  out = hself + bias +
// hdst * acc/den.  (b_edge already folded into e_s, b_att into logits.)
// ---------------------------------------------------------------------------
__global__ void nig_reduce(const int* __restrict__ offs,
                           const float* __restrict__ logits_s,
                           const int* __restrict__ src_s,
                           const short* __restrict__ ewe_s,
                           const short* __restrict__ hsB,
                           const float* __restrict__ hdst, const float* __restrict__ hself,
                           const float* __restrict__ bias, float* __restrict__ out) {
  const int node = (blockIdx.x * blockDim.x + threadIdx.x) >> 6;
  const int ln = threadIdx.x & 63;
  if (node >= NN) return;
  const int b0 = offs[node], b1 = offs[node + 1];
  const int deg = b1 - b0;
  const int c2 = ln * 2;

  float mx = -1e30f;
  for (int i = ln; i < deg; i += 64) mx = fmaxf(mx, logits_s[b0 + i]);
#pragma unroll
  for (int o = 32; o > 0; o >>= 1) mx = fmaxf(mx, __shfl_xor(mx, o, 64));

  float den = 0.f, a0 = 0.f, a1 = 0.f;
#pragma unroll 2
  for (int i = 0; i < deg; ++i) {
    float p = __expf(logits_s[b0 + i] - mx);
    uint32_t ee = *(const uint32_t*)(ewe_s + (size_t)(b0 + i) * 128 + c2);
    int sn = src_s[b0 + i];
    uint32_t hh = *(const uint32_t*)(hsB + (size_t)sn * 128 + c2);
    a0 += p * bf2f(ee & 0xffffu) * bf2f(hh & 0xffffu);
    a1 += p * bf2f(ee >> 16) * bf2f(hh >> 16);
    den += p;
  }
  float inv = (deg > 0) ? 1.0f / den : 0.f;
  f32x2 hd = *(const f32x2*)(hdst + (size_t)node * 128 + c2);
  f32x2 hs = *(const f32x2*)(hself + (size_t)node * 128 + c2);
  f32x2 bb = *(const f32x2*)(bias + c2);
  f32x2 o;
  o[0] = hs[0] + bb[0] + hd[0] * a0 * inv;
  o[1] = hs[1] + bb[1] + hd[1] * a1 * inv;
  *(f32x2*)(out + (size_t)node * 128 + c2) = o;
}

// ---------------------------------------------------------------------------
extern "C" void kernel_launch(void* const* d_in, const int* in_sizes, int n_in,
                              void* d_out, int out_size, void* d_ws, size_t ws_size,
                              hipStream_t stream) {
  const float* feat      = (const float*)d_in[0];
  const float* edge_w    = (const float*)d_in[1];
  const float* W_neigh   = (const float*)d_in[2];
  const float* W_dstM    = (const float*)d_in[3];
  const float* W_self    = (const float*)d_in[4];
  const float* W_edge    = (const float*)d_in[5];
  const float* b_edge    = (const float*)d_in[6];
  const float* W_prj_src = (const float*)d_in[7];
  const float* b_prj_src = (const float*)d_in[8];
  const float* W_prj_dst = (const float*)d_in[9];
  const float* b_prj_dst = (const float*)d_in[10];
  const float* W_prj_edge= (const float*)d_in[11];
  const float* b_prj_edge= (const float*)d_in[12];
  const float* alpha     = (const float*)d_in[13];
  const float* W_att     = (const float*)d_in[14];
  const float* b_att     = (const float*)d_in[15];
  const float* bias      = (const float*)d_in[16];
  const int*   src       = (const int*)d_in[17];
  const int*   dst       = (const int*)d_in[18];
  float* out = (float*)d_out;

  char* ws = (char*)d_ws;
  size_t off = 0;
  auto alloc = [&](size_t bytes) -> void* {
    void* p = ws + off;
    off = (off + bytes + 511) & ~(size_t)511;
    return p;
  };
  short* img_edge = (short*)alloc((size_t)8 * 256 * 64);       // 256 KB
  short* img_node = (short*)alloc((size_t)5 * 8 * 128 * 64);   // 640 KB
  float* bsum     = (float*)alloc(128 * 4);
  short* hwS      = (short*)alloc((size_t)NN * 128 * 2);
  short* hwD      = (short*)alloc((size_t)NN * 128 * 2);
  short* hsB      = (short*)alloc((size_t)NN * 128 * 2);
  float* hdst     = (float*)alloc((size_t)NN * 128 * 4);
  float* hself    = (float*)alloc((size_t)NN * 128 * 4);
  float* logits_s = (float*)alloc((size_t)NE * 4);
  int*   src_s    = (int*)alloc((size_t)NE * 4);
  short* ewe_s    = (short*)alloc((size_t)NE * 128 * 2);       // 82 MB
  int*   deg      = (int*)alloc((size_t)NN * 4);
  int*   offsb    = (int*)alloc((size_t)(NN + 1) * 4);
  int*   cursor   = (int*)alloc((size_t)NN * 4);
  int*   rank     = (int*)alloc((size_t)NE * 4);

  hipMemsetAsync(deg, 0, (size_t)NN * 4, stream);

  // CSR build (independent of GEMMs; provides rank[] for sorted stores)
  nig_count<<<dim3((NE + 255) / 256), 256, 0, stream>>>(dst, deg);
  nig_scan<<<dim3(1), 1024, 0, stream>>>(deg, offsb, cursor);
  nig_scatter<<<dim3((NE + 255) / 256), 256, 0, stream>>>(dst, cursor, rank);

  nig_prep<<<dim3(112), 256, 0, stream>>>(
      W_prj_edge, W_edge, W_prj_src, W_prj_dst, W_neigh, W_dstM, W_self,
      b_prj_src, b_prj_dst, b_prj_edge, img_edge, img_node, bsum);

  nig_gemm_node<<<dim3(79, 5), 256, 0, stream>>>(feat, NN, img_node,
                                                 hwS, hwD, hsB, hdst, hself);

  nig_gemm_edge<<<dim3(NE / 128), 256, 0, stream>>>(
      edge_w, img_edge, hwS, hwD, bsum, W_att, b_att, alpha, b_edge,
      src, dst, rank, logits_s, src_s, ewe_s);

  nig_reduce<<<dim3((NN + 3) / 4), 256, 0, stream>>>(offsb, logits_s, src_s, ewe_s,
                                                     hsB, hdst, hself, bias, out);
}